// Round 5
// baseline (583.155 us; speedup 1.0000x reference)
//
#include <hip/hip_runtime.h>
#include <cstddef>

// Vanilla tanh-RNN: B=4096, T=2048, I=4, H=20, then Linear(20->4) on h_last.
//
// Round-5 design: K-split, 2 waves/SIMD.
//
// HW model from R3/R4 (dur invariant under total schedule restructure;
// VALU busy-cycles == 4 x static inst count in both): a single wave issues
// at most ~1 VALU inst per 4 cycles. The 2-cyc SIMD-32 rate needs >=2
// waves/SIMD interleaving. With 4096 batch elements, 2 waves/SIMD requires
// 2 elements/wave = 32 lanes/element.
//
// K-split across the element's two 16-lane rows (DPP ctrl immediates are
// shared wave-wide, per-lane WEIGHTS are not — so both rows run the same
// row_ror:0..7 sweep but with row-specific weight permutations):
//   row m lane jj holds h_{u}, u=(jj+8m)&15; rotation r delivers h_{u-r}.
//   row 0 accumulates k=u-7..u, row 1 k=u+1..u+8 of target unit jj ->
//   complementary halves. Units 16..19 (hBr, quad-replicated) contribute
//   via shared quad_perm; A-quads weighted only in row 0, B-quads only in
//   row 1 (per-lane zero weights). xi split: row 0 takes x components 0,1
//   (+ biases), row 1 takes 2,3 — rows read different float2 from LDS.
//   Partials combine with 3 ds_bpermute (LDS pipe, off the VALU):
//     sA(lane) = pa[row0 lane u] + pa[row1 lane u]   (2 bpermutes)
//     sB(lane) = pb + pa-partner (lane^16)            (1 bpermute)
//   tanh(sA) -> h_{u} lands exactly where each lane needs its own state.
//
// tanh argument pre-scaling: all W_ih/W_hh/biases are scaled by 2*log2(e)
// at setup so tanh = 1 - 2*rcp(exp2(s)+1) needs no per-step multiply.
//
// Zero barriers: each element lives entirely within one wave (LDS staging
// + bpermute are intra-wave; DS pipe is in-order per wave — validated R1-R4).

constexpr int Tn   = 2048;
constexpr int Hn   = 20;
constexpr int EPB  = 8;    // elements per 256-thread block (32 lanes each)
constexpr int SB   = 16;   // steps per staging block
constexpr int NBLK = Tn / SB;
constexpr int XSTR = 33;   // float2 stride per element in LDS (pad de-alias)

template <int CTRL>
__device__ __forceinline__ float dppf(float src) {
    int r = __builtin_amdgcn_update_dpp(
        __builtin_bit_cast(int, src), __builtin_bit_cast(int, src),
        CTRL, 0xF, 0xF, false);
    return __builtin_bit_cast(float, r);
}

__device__ __forceinline__ float bperm(int byteaddr, float v) {
    return __builtin_bit_cast(
        float, __builtin_amdgcn_ds_bpermute(byteaddr, __builtin_bit_cast(int, v)));
}

__global__ __launch_bounds__(256, 2) void rnn_fwd(
    const float* __restrict__ x,     // [B, T, 4]
    const float* __restrict__ h0,    // [B, 20]
    const float* __restrict__ W_ih,  // [20, 4]
    const float* __restrict__ W_hh,  // [20, 20]
    const float* __restrict__ b_ih,  // [20]
    const float* __restrict__ b_hh,  // [20]
    const float* __restrict__ fc_w,  // [4, 20]
    const float* __restrict__ fc_b,  // [4]
    float* __restrict__ out)         // [B, 4]
{
    __shared__ __align__(8) float2 xl[2][EPB][XSTR];
    __shared__ float hsh[EPB][24];

    const int tid  = threadIdx.x;
    const int lane = tid & 63;            // wave lane
    const int l32  = tid & 31;            // lane within element group
    const int jj   = l32 & 15;            // row position = A-target unit
    const int m    = (l32 >> 4) & 1;      // k-half (row) index
    const int e    = tid >> 5;            // element slot in block (0..7)
    const int b    = blockIdx.x * EPB + e;
    const int uOwn = (jj + 8 * m) & 15;   // unit whose h this lane holds
    const int uB   = 16 + (jj & 3);       // B-target unit (all lanes)

    const float S = 2.88539008177792681472f;  // 2*log2(e) pre-scale

    // ---- per-lane weights ----
    float wa[8], wb[8];                   // rotation weights, r = 0..7
#pragma unroll
    for (int r = 0; r < 8; ++r) {
        const int k = (uOwn - r) & 15;    // unit value delivered by row_ror:r
        wa[r] = S * W_hh[jj * Hn + k];    // target unit jj (both rows)
        wb[r] = S * W_hh[uB * Hn + k];    // target unit uB (both rows)
    }
    float waq[4], wbq[4];                 // quad terms h16..19: A in row0, B in row1
#pragma unroll
    for (int c = 0; c < 4; ++c) {
        waq[c] = m ? 0.0f : S * W_hh[jj * Hn + 16 + c];
        wbq[c] = m ? S * W_hh[uB * Hn + 16 + c] : 0.0f;
    }
    // xi: row m handles x components 2m, 2m+1
    float xia0 = S * W_ih[jj * 4 + 2 * m];
    float xia1 = S * W_ih[jj * 4 + 2 * m + 1];
    float xib0 = S * W_ih[uB * 4 + 2 * m];
    float xib1 = S * W_ih[uB * 4 + 2 * m + 1];
    float biasA = m ? 0.0f : S * (b_ih[jj] + b_hh[jj]);
    float biasB = m ? 0.0f : S * (b_ih[uB] + b_hh[uB]);

    // Pin loop-invariants in VGPRs (R1: without this the compiler remats
    // weight loads inside the step loop).
#pragma unroll
    for (int r = 0; r < 8; ++r) asm volatile("" : "+v"(wa[r]), "+v"(wb[r]));
#pragma unroll
    for (int c = 0; c < 4; ++c) asm volatile("" : "+v"(waq[c]), "+v"(wbq[c]));
    asm volatile("" : "+v"(xia0), "+v"(xia1), "+v"(xib0), "+v"(xib1),
                       "+v"(biasA), "+v"(biasB));

    // bpermute byte addresses (within the wave's 64 lanes)
    const int g32    = lane & 32;                 // element group base lane
    const int adrA1  = (g32 + uOwn) << 2;         // row0 partial of unit uOwn
    const int adrA2  = (g32 + 16 + uOwn) << 2;    // row1 partial of unit uOwn
    const int adrB   = (lane ^ 16) << 2;          // k-half partner (same jj)

    // ---- initial state ----
    float hA  = h0[b * Hn + uOwn];        // h of this lane's own unit
    float hBr = h0[b * Hn + uB];          // h_{16+(jj&3)}, every lane

    const float2* __restrict__ xg =
        reinterpret_cast<const float2*>(x) + (size_t)b * (Tn * 2);

    auto step = [&](float2 xv) {
        // xi + bias (2 chains per target)
        float pa0 = __builtin_fmaf(xv.x, xia0, biasA);
        float pb0 = __builtin_fmaf(xv.x, xib0, biasB);
        float pa1 = xv.y * xia1;
        float pb1 = xv.y * xib1;
        // r = 0: own h, no DPP
        pa0 = __builtin_fmaf(hA, wa[0], pa0);
        pb0 = __builtin_fmaf(hA, wb[0], pb0);
        // r = 1..7: shared row_ror sweep (batched movs, then FMAs)
        float rv1 = dppf<0x121>(hA);
        float rv2 = dppf<0x122>(hA);
        float rv3 = dppf<0x123>(hA);
        float rv4 = dppf<0x124>(hA);
        float rv5 = dppf<0x125>(hA);
        float rv6 = dppf<0x126>(hA);
        float rv7 = dppf<0x127>(hA);
        pa1 = __builtin_fmaf(rv1, wa[1], pa1);
        pb1 = __builtin_fmaf(rv1, wb[1], pb1);
        pa0 = __builtin_fmaf(rv2, wa[2], pa0);
        pb0 = __builtin_fmaf(rv2, wb[2], pb0);
        pa1 = __builtin_fmaf(rv3, wa[3], pa1);
        pb1 = __builtin_fmaf(rv3, wb[3], pb1);
        pa0 = __builtin_fmaf(rv4, wa[4], pa0);
        pb0 = __builtin_fmaf(rv4, wb[4], pb0);
        pa1 = __builtin_fmaf(rv5, wa[5], pa1);
        pb1 = __builtin_fmaf(rv5, wb[5], pb1);
        pa0 = __builtin_fmaf(rv6, wa[6], pa0);
        pb0 = __builtin_fmaf(rv6, wb[6], pb0);
        pa1 = __builtin_fmaf(rv7, wa[7], pa1);
        pb1 = __builtin_fmaf(rv7, wb[7], pb1);
        // units 16..19 via shared quad_perm (A-weights live in row0 only,
        // B-weights in row1 only — per-lane zeros keep each term counted once)
        float qv0 = dppf<0x00>(hBr);
        float qv1 = dppf<0x55>(hBr);
        float qv2 = dppf<0xAA>(hBr);
        float qv3 = dppf<0xFF>(hBr);
        pa0 = __builtin_fmaf(qv0, waq[0], pa0);
        pb0 = __builtin_fmaf(qv0, wbq[0], pb0);
        pa1 = __builtin_fmaf(qv1, waq[1], pa1);
        pb1 = __builtin_fmaf(qv1, wbq[1], pb1);
        pa0 = __builtin_fmaf(qv2, waq[2], pa0);
        pb0 = __builtin_fmaf(qv2, wbq[2], pb0);
        pa1 = __builtin_fmaf(qv3, waq[3], pa1);
        pb1 = __builtin_fmaf(qv3, wbq[3], pb1);
        float pa = pa0 + pa1;
        float pb = pb0 + pb1;
        // combine k-halves across rows (LDS pipe, off the VALU cadence)
        float oa1 = bperm(adrA1, pa);
        float oa2 = bperm(adrA2, pa);
        float obx = bperm(adrB,  pb);
        float sA = oa1 + oa2;             // full dot of unit uOwn
        float sB = pb  + obx;             // full dot of unit uB
        // tanh (weights pre-scaled: s already in exp2 domain)
        float eA = __builtin_amdgcn_exp2f(sA);
        float eB = __builtin_amdgcn_exp2f(sB);
        float rA = __builtin_amdgcn_rcpf(eA + 1.0f);
        float rB = __builtin_amdgcn_rcpf(eB + 1.0f);
        hA  = __builtin_fmaf(-2.0f, rA, 1.0f);
        hBr = __builtin_fmaf(-2.0f, rB, 1.0f);
    };

    // ---- prologue: stage block 0 (32 float2 per element, lane l32 -> slot l32) ----
    xl[0][e][l32] = xg[l32];
    float2 q0 = xl[0][e][m];              // row m reads float2 index 2s+m
    float2 q1 = xl[0][e][2 + m];
    float2 q2 = xl[0][e][4 + m];

    int cur = 0;
#pragma unroll 1
    for (int k = 0; k < NBLK; ++k) {
        const int kn = (k + 1 < NBLK) ? (k + 1) : (NBLK - 1);  // tail reload
        float2 xr = xg[kn * 32 + l32];    // global load at block TOP (~13 steps slack)
        const int nxt = cur ^ 1;
#pragma unroll
        for (int s = 0; s < SB - 3; ++s) {                     // s = 0..12
            float2 xv = q0; q0 = q1; q1 = q2;
            q2 = xl[cur][e][2 * (s + 3) + m];                  // 3-step lookahead
            step(xv);
        }
        xl[nxt][e][l32] = xr;             // prior reads of nxt already issued
        { float2 xv = q0; q0 = q1; q1 = q2; q2 = xl[nxt][e][0 + m]; step(xv); }
        { float2 xv = q0; q0 = q1; q1 = q2; q2 = xl[nxt][e][2 + m]; step(xv); }
        { float2 xv = q0; q0 = q1; q1 = q2; q2 = xl[nxt][e][4 + m]; step(xv); }
        cur = nxt;
    }

    // ---- epilogue: out[b][o] = fc_b[o] + sum_k h[k] * fc_w[o][k] ----
    if (m == 0) hsh[e][jj] = hA;          // row0 lane jj holds h_jj
    if (m == 0 && jj < 4) hsh[e][16 + jj] = hBr;   // h_{16+jj}
    if (m == 0 && jj < 4) {
        float o = fc_b[jj];
#pragma unroll
        for (int k = 0; k < Hn; ++k)
            o = __builtin_fmaf(hsh[e][k], fc_w[jj * Hn + k], o);
        out[b * 4 + jj] = o;
    }
}

extern "C" void kernel_launch(void* const* d_in, const int* in_sizes, int n_in,
                              void* d_out, int out_size, void* d_ws, size_t ws_size,
                              hipStream_t stream) {
    const float* x    = (const float*)d_in[0];
    const float* h0   = (const float*)d_in[1];
    const float* W_ih = (const float*)d_in[2];
    const float* W_hh = (const float*)d_in[3];
    const float* b_ih = (const float*)d_in[4];
    const float* b_hh = (const float*)d_in[5];
    const float* fc_w = (const float*)d_in[6];
    const float* fc_b = (const float*)d_in[7];
    float* out = (float*)d_out;

    // 4096 elements / 8 per block = 512 blocks = 2048 waves = 2 waves/SIMD.
    rnn_fwd<<<dim3(512), dim3(256), 0, stream>>>(x, h0, W_ih, W_hh, b_ih, b_hh,
                                                 fc_w, fc_b, out);
}

// Round 6
// 418.533 us; speedup vs baseline: 1.3933x; 1.3933x over previous
//
#include <hip/hip_runtime.h>
#include <cstddef>

// Vanilla tanh-RNN: B=4096, T=2048, I=4, H=20, then Linear(20->4) on h_last.
//
// Round-6: fused v_fmac_f32_dpp step (inline asm), exact instruction count.
//
// Empirical law from R3/R4/R5: wall = ~5 cyc x per-SIMD VALU inst count per
// step, invariant under scheduling (R4) and wave count (R5: 2 waves/SIMD
// gave ZERO overlap, wall tracked total inst count). Only lever: fewer
// instructions. VOP2 v_fmac_f32 takes a DPP modifier on src0, so each
// "rotate h, multiply by weight, accumulate" is ONE instruction instead of
// a v_mov_b32_dpp + v_fma_f32 pair: 57 insts -> 38.
//
// Layout identical to R4 (validated twice): 16 lanes/element, 4 elem/wave,
// 1024 waves = 1 wave/SIMD. Lane j holds h_j (hA) and h_{16+(j&3)} (hBr,
// quad-replicated). row_ror:r delivers h_{(j-r)&15}; weights pre-permuted
// wA[r] = W_hh[j][(j-r)&15]. Units 16..19 via quad_perm:[c,c,c,c] on hBr.
// All-lanes-B: every lane accumulates unit 16+(j&3)'s full dot, so tanh(cB)
// lands already quad-replicated.
//
// DPP hazard note: the first DPP reads of hA/hBr in a step are the rotation
// fmacs, which depend on accumulators initialized by the ~10-inst xi block;
// that separation covers the VALU-write -> DPP-read wait states.
//
// x staging: R3/R4's wave-local LDS double buffer, 3-step register
// lookahead, zero barriers (intra-wave DS program order, validated R1-R5).

constexpr int Tn   = 2048;
constexpr int Hn   = 20;
constexpr int EPB  = 16;   // elements per 256-thread block
constexpr int SB   = 16;   // steps per staging block
constexpr int NBLK = Tn / SB;

__global__ __launch_bounds__(256, 1) void rnn_fwd(
    const float* __restrict__ x,     // [B, T, 4]
    const float* __restrict__ h0,    // [B, 20]
    const float* __restrict__ W_ih,  // [20, 4]
    const float* __restrict__ W_hh,  // [20, 20]
    const float* __restrict__ b_ih,  // [20]
    const float* __restrict__ b_hh,  // [20]
    const float* __restrict__ fc_w,  // [4, 20]
    const float* __restrict__ fc_b,  // [4]
    float* __restrict__ out)         // [B, 4]
{
    __shared__ __align__(16) float4 xlds[2][EPB][SB + 1];
    __shared__ float hsh[EPB][24];

    const int tid = threadIdx.x;
    const int j   = tid & 15;             // lane within row = A-target unit
    const int e   = tid >> 4;             // element slot in block (0..15)
    const int b   = blockIdx.x * EPB + e;
    const int uB  = 16 + (j & 3);         // B-target unit

    // ---- per-lane weights (rotation-permuted), pre-scaled by 2*log2(e)
    // so tanh needs no argument multiply: tanh = 1 - 2*rcp(exp2(s)+1).
    const float S = 2.88539008177792681472f;
    float wA[16], wB[16];
#pragma unroll
    for (int r = 0; r < 16; ++r) {
        const int k = (j - r) & 15;       // unit delivered by row_ror:r
        wA[r] = S * W_hh[j  * Hn + k];
        wB[r] = S * W_hh[uB * Hn + k];
    }
    float wAq[4], wBq[4], xiA[4], xiB[4];
#pragma unroll
    for (int c = 0; c < 4; ++c) {
        wAq[c] = S * W_hh[j  * Hn + 16 + c];
        wBq[c] = S * W_hh[uB * Hn + 16 + c];
        xiA[c] = S * W_ih[j  * 4 + c];
        xiB[c] = S * W_ih[uB * 4 + c];
    }
    float biasA = S * (b_ih[j]  + b_hh[j]);
    float biasB = S * (b_ih[uB] + b_hh[uB]);

#pragma unroll
    for (int r = 0; r < 16; ++r) asm volatile("" : "+v"(wA[r]), "+v"(wB[r]));
#pragma unroll
    for (int c = 0; c < 4; ++c)
        asm volatile("" : "+v"(wAq[c]), "+v"(wBq[c]), "+v"(xiA[c]), "+v"(xiB[c]));
    asm volatile("" : "+v"(biasA), "+v"(biasB));

    // ---- initial state ----
    float hA  = h0[b * Hn + j];
    float hBr = h0[b * Hn + uB];          // h_{16+(j&3)}: quad-replicated by layout

    const float4* __restrict__ xp =
        reinterpret_cast<const float4*>(x) + (size_t)b * Tn;

    // One rotation-FMA: ACC += dpp_row_ror<R>(hA) * W   (single VOP2-DPP inst)
#define ROT_FMAC(R, ACC, W)                                                  \
    asm("v_fmac_f32_dpp %0, %1, %2 row_ror:" #R " row_mask:0xf bank_mask:0xf"\
        : "+v"(ACC) : "v"(hA), "v"(W))
    // Quad broadcast FMA: ACC += quad_perm<[c,c,c,c]>(hBr) * W
#define QUAD_FMAC(CSTR, ACC, W)                                              \
    asm("v_fmac_f32_dpp %0, %1, %2 quad_perm:[" CSTR "] row_mask:0xf bank_mask:0xf" \
        : "+v"(ACC) : "v"(hBr), "v"(W))

    auto step = [&](float4 xv) {
        // xi + bias (4 accumulator chains; also spaces tanh's hA/hBr writes
        // away from the DPP reads below)
        float a0 = __builtin_fmaf(xv.x, xiA[0], biasA);
        float c0 = __builtin_fmaf(xv.x, xiB[0], biasB);
        float a1 = xv.y * xiA[1];
        float c1 = xv.y * xiB[1];
        a0 = __builtin_fmaf(xv.z, xiA[2], a0);
        c0 = __builtin_fmaf(xv.z, xiB[2], c0);
        a1 = __builtin_fmaf(xv.w, xiA[3], a1);
        c1 = __builtin_fmaf(xv.w, xiB[3], c1);
        // r = 0: own h, plain FMA
        a0 = __builtin_fmaf(hA, wA[0], a0);
        c0 = __builtin_fmaf(hA, wB[0], c0);
        // r = 1..15: fused rotation FMAs, round-robin over 4 chains
        ROT_FMAC(1,  a1, wA[1]);  ROT_FMAC(1,  c1, wB[1]);
        ROT_FMAC(2,  a0, wA[2]);  ROT_FMAC(2,  c0, wB[2]);
        ROT_FMAC(3,  a1, wA[3]);  ROT_FMAC(3,  c1, wB[3]);
        ROT_FMAC(4,  a0, wA[4]);  ROT_FMAC(4,  c0, wB[4]);
        ROT_FMAC(5,  a1, wA[5]);  ROT_FMAC(5,  c1, wB[5]);
        ROT_FMAC(6,  a0, wA[6]);  ROT_FMAC(6,  c0, wB[6]);
        ROT_FMAC(7,  a1, wA[7]);  ROT_FMAC(7,  c1, wB[7]);
        ROT_FMAC(8,  a0, wA[8]);  ROT_FMAC(8,  c0, wB[8]);
        ROT_FMAC(9,  a1, wA[9]);  ROT_FMAC(9,  c1, wB[9]);
        ROT_FMAC(10, a0, wA[10]); ROT_FMAC(10, c0, wB[10]);
        ROT_FMAC(11, a1, wA[11]); ROT_FMAC(11, c1, wB[11]);
        ROT_FMAC(12, a0, wA[12]); ROT_FMAC(12, c0, wB[12]);
        ROT_FMAC(13, a1, wA[13]); ROT_FMAC(13, c1, wB[13]);
        ROT_FMAC(14, a0, wA[14]); ROT_FMAC(14, c0, wB[14]);
        ROT_FMAC(15, a1, wA[15]); ROT_FMAC(15, c1, wB[15]);
        // units 16..19: fused quad_perm broadcast FMAs
        QUAD_FMAC("0,0,0,0", a0, wAq[0]); QUAD_FMAC("0,0,0,0", c0, wBq[0]);
        QUAD_FMAC("1,1,1,1", a1, wAq[1]); QUAD_FMAC("1,1,1,1", c1, wBq[1]);
        QUAD_FMAC("2,2,2,2", a0, wAq[2]); QUAD_FMAC("2,2,2,2", c0, wBq[2]);
        QUAD_FMAC("3,3,3,3", a1, wAq[3]); QUAD_FMAC("3,3,3,3", c1, wBq[3]);
        // combine + tanh (weights pre-scaled: s already in exp2 domain)
        float sA = a0 + a1;
        float sB = c0 + c1;
        float eA = __builtin_amdgcn_exp2f(sA);
        float eB = __builtin_amdgcn_exp2f(sB);
        float rA = __builtin_amdgcn_rcpf(eA + 1.0f);
        float rB = __builtin_amdgcn_rcpf(eB + 1.0f);
        hA  = __builtin_fmaf(-2.0f, rA, 1.0f);
        hBr = __builtin_fmaf(-2.0f, rB, 1.0f);
    };

    // ---- prologue: stage block 0, prime 3-deep queue ----
    xlds[0][e][j] = xp[j];                // lane j -> row j (coalesced)
    float4 q0 = xlds[0][e][0];
    float4 q1 = xlds[0][e][1];
    float4 q2 = xlds[0][e][2];

    int cur = 0;
#pragma unroll 1
    for (int k = 0; k < NBLK; ++k) {
        const int kn = (k + 1 < NBLK) ? (k + 1) : (NBLK - 1);  // tail reload
        float4 xr = xp[kn * SB + j];      // global load at block TOP (~13 steps slack)
        const int nxt = cur ^ 1;
#pragma unroll
        for (int s = 0; s < SB - 3; ++s) {                     // s = 0..12
            float4 xv = q0; q0 = q1; q1 = q2;
            q2 = xlds[cur][e][s + 3];     // 3-step LDS lookahead
            step(xv);
        }
        xlds[nxt][e][j] = xr;             // prior reads of nxt already issued
        { float4 xv = q0; q0 = q1; q1 = q2; q2 = xlds[nxt][e][0]; step(xv); }
        { float4 xv = q0; q0 = q1; q1 = q2; q2 = xlds[nxt][e][1]; step(xv); }
        { float4 xv = q0; q0 = q1; q1 = q2; q2 = xlds[nxt][e][2]; step(xv); }
        cur = nxt;
    }
#undef ROT_FMAC
#undef QUAD_FMAC

    // ---- epilogue: out[b][m] = fc_b[m] + sum_k h[k] * fc_w[m][k] ----
    hsh[e][j] = hA;                       // units 0..15
    if (j < 4) hsh[e][16 + j] = hBr;      // lane j holds unit 16+j
    if (j < 4) {
        float o = fc_b[j];
#pragma unroll
        for (int k = 0; k < Hn; ++k)
            o = __builtin_fmaf(hsh[e][k], fc_w[j * Hn + k], o);
        out[b * 4 + j] = o;
    }
}

extern "C" void kernel_launch(void* const* d_in, const int* in_sizes, int n_in,
                              void* d_out, int out_size, void* d_ws, size_t ws_size,
                              hipStream_t stream) {
    const float* x    = (const float*)d_in[0];
    const float* h0   = (const float*)d_in[1];
    const float* W_ih = (const float*)d_in[2];
    const float* W_hh = (const float*)d_in[3];
    const float* b_ih = (const float*)d_in[4];
    const float* b_hh = (const float*)d_in[5];
    const float* fc_w = (const float*)d_in[6];
    const float* fc_b = (const float*)d_in[7];
    float* out = (float*)d_out;

    // 4096 elements / 16 per block = 256 blocks = 1024 waves = 1 wave/SIMD.
    rnn_fwd<<<dim3(256), dim3(256), 0, stream>>>(x, h0, W_ih, W_hh, b_ih, b_hh,
                                                 fc_w, fc_b, out);
}